// Round 20
// baseline (65.007 us; speedup 1.0000x reference)
//
#include <hip/hip_runtime.h>

#define N_NODES 50000
#define N_EDGES 800000
#define D 128

#define NBLK 250                  // partition blocks (edge base 16B-aligned)
#define EPB (N_EDGES / NBLK)      // 3200 edges per block
#define NQ (EPB / 4)              // 800 int4 quads per block
#define NBKT 196                  // coarse buckets of 256 nodes
#define CAP 6144                  // fixed slots per bucket

typedef __attribute__((ext_vector_type(8))) short bf16x8;
typedef __attribute__((ext_vector_type(4))) float f32x4;

// ---------------- workspace layout (bytes) ----------------
static const size_t OFF_TOT  = 0;          // int[196] bucket edge count
static const size_t OFF_WT   = 1024;       // ushort[128*128] bf16 W^T [n][k]
static const size_t OFF_H    = 33792;      // int[196*256] per-(bucket,block) counts (stride 256)
static const size_t OFF_BB   = 234496;     // int[196*256] rel scatter bases (stride 256)
static const size_t OFF_DEG  = 435200;     // int[50000]
static const size_t OFF_OFFS = 635200;     // int[50000]
static const size_t OFF_IVS  = 835200;     // float2[50000] {inv, scale}
static const size_t OFF_REC  = 1235200;    // uint[196*6144] (src | dstLocal<<16)
static const size_t OFF_CSR  = 6052096;    // ushort[196*6144]
static const size_t OFF_XWQ  = 8460544;    // int8[50000*128]
// total: 14,860,544 bytes

#define BM 64
#define NB_GEMM ((N_NODES + BM - 1) / BM)   // 782

__device__ __forceinline__ unsigned short f2bf(float f) {
    unsigned int u = __float_as_uint(f);
    unsigned int r = (u + 0x7fffu + ((u >> 16) & 1u)) >> 16;   // RNE
    return (unsigned short)r;
}
__device__ __forceinline__ float sb(unsigned int u, int i) {
    return (float)((int)(u << (24 - 8 * i)) >> 24);
}

// ---- launch 1: pass-A histogram (blocks 0..249, int4 edge loads) ∥ Wt conv (250..313) ----
__global__ __launch_bounds__(256) void k_pre(const int* __restrict__ dst,
                                             int* __restrict__ H,
                                             const float* __restrict__ W,
                                             unsigned short* __restrict__ Wt) {
    __shared__ unsigned int cnt[256];
    int bid = blockIdx.x, t = threadIdx.x;
    if (bid >= NBLK) {
        int idx = (bid - NBLK) * 256 + t;   // 0..16383
        int n = idx >> 7, k = idx & 127;
        Wt[n * D + k] = f2bf(W[k * D + n]);
        return;
    }
    cnt[t] = 0;
    __syncthreads();
    int e0 = bid * EPB;
    for (int q = t; q < NQ; q += 256) {
        int4 d4 = *(const int4*)&dst[e0 + q * 4];
        atomicAdd(&cnt[d4.x >> 8], 1u);
        atomicAdd(&cnt[d4.y >> 8], 1u);
        atomicAdd(&cnt[d4.z >> 8], 1u);
        atomicAdd(&cnt[d4.w >> 8], 1u);
    }
    __syncthreads();
    if (t < NBKT) H[t * 256 + bid] = (int)cnt[t];
}

// ---- launch 2: per-bucket scan over blocks (independent) ----
__global__ __launch_bounds__(256) void k_pB(const int* __restrict__ H,
                                            int* __restrict__ BB,
                                            int* __restrict__ TOT) {
    int k = blockIdx.x, t = threadIdx.x;
    int w = t >> 6, l = t & 63;
    int v = (t < NBLK) ? H[k * 256 + t] : 0;
    int s = v;
    #pragma unroll
    for (int d = 1; d < 64; d <<= 1) {
        int u = __shfl_up(s, d, 64);
        if (l >= d) s += u;
    }
    __shared__ int wtot[4], woff[4];
    if (l == 63) wtot[w] = s;
    __syncthreads();
    if (t == 0) {
        woff[0] = 0; woff[1] = wtot[0];
        woff[2] = wtot[0] + wtot[1]; woff[3] = wtot[0] + wtot[1] + wtot[2];
    }
    __syncthreads();
    int excl = s - v + woff[w];
    BB[k * 256 + t] = excl;
    if (t == 255) TOT[k] = excl + v;
}

// ---- launch 3: rank-capturing re-histogram + record scatter (int4 edge loads) ----
__global__ __launch_bounds__(512) void k_pC(const int* __restrict__ src,
                                            const int* __restrict__ dst,
                                            const int* __restrict__ BB,
                                            unsigned int* __restrict__ rec) {
    __shared__ unsigned int cnt[200];
    __shared__ int myBB[NBKT];
    int b = blockIdx.x, t = threadIdx.x;
    if (t < 200) cnt[t] = 0;
    if (t < NBKT) myBB[t] = t * CAP + BB[t * 256 + b];
    __syncthreads();
    int e0 = b * EPB;
    for (int q = t; q < NQ; q += 512) {
        int4 d4 = *(const int4*)&dst[e0 + q * 4];
        int4 s4 = *(const int4*)&src[e0 + q * 4];
        {
            int k = d4.x >> 8;
            unsigned int r = atomicAdd(&cnt[k], 1u);
            rec[myBB[k] + (int)r] = (unsigned int)s4.x | ((unsigned int)(d4.x & 255) << 16);
        }
        {
            int k = d4.y >> 8;
            unsigned int r = atomicAdd(&cnt[k], 1u);
            rec[myBB[k] + (int)r] = (unsigned int)s4.y | ((unsigned int)(d4.y & 255) << 16);
        }
        {
            int k = d4.z >> 8;
            unsigned int r = atomicAdd(&cnt[k], 1u);
            rec[myBB[k] + (int)r] = (unsigned int)s4.z | ((unsigned int)(d4.z & 255) << 16);
        }
        {
            int k = d4.w >> 8;
            unsigned int r = atomicAdd(&cnt[k], 1u);
            rec[myBB[k] + (int)r] = (unsigned int)s4.w | ((unsigned int)(d4.w & 255) << 16);
        }
    }
}

// ---- launch 4: pass D (blocks 0..195) ∥ GEMM (A direct from global) + int8 quant ----
__global__ __launch_bounds__(256) void k_mid(const unsigned int* __restrict__ rec,
                                             const int* __restrict__ TOT,
                                             int* __restrict__ deg,
                                             int* __restrict__ offs,
                                             float* __restrict__ ivs,
                                             unsigned short* __restrict__ csr,
                                             const float* __restrict__ X,
                                             const unsigned short* __restrict__ Wt,
                                             char* __restrict__ XWq) {
    __shared__ unsigned short sB[D * D];     // 32KB (gemm B) / pD scratch
    __shared__ int wtot[4], woff[4];
    int bid = blockIdx.x;
    int t = threadIdx.x;
    int w = t >> 6, l = t & 63;

    if (bid >= NBKT) {
        // ---------------- GEMM + per-row int8 quantization ----------------
        int r0 = (bid - NBKT) * BM;

        #pragma unroll
        for (int p = 0; p < 8; ++p) {
            int e = p * 2048 + t * 8;
            int n = e >> 7, k = e & 127;
            uint4 v = *(const uint4*)&Wt[e];
            int idx = n * D + (((k >> 3) ^ (n & 7)) << 3);
            *(uint4*)&sB[idx] = v;
        }
        __syncthreads();

        int arow = w * 16 + (l & 15);
        int xrow = r0 + arow;
        bool okr = (xrow < N_NODES);
        f32x4 acc[8];
        #pragma unroll
        for (int i = 0; i < 8; ++i) acc[i] = (f32x4){0.f, 0.f, 0.f, 0.f};

        #pragma unroll
        for (int kk = 0; kk < 4; ++kk) {
            int g = kk * 4 + (l >> 4);
            float4 xa = make_float4(0.f, 0.f, 0.f, 0.f);
            float4 xb = make_float4(0.f, 0.f, 0.f, 0.f);
            if (okr) {
                xa = *(const float4*)&X[xrow * D + g * 8];
                xb = *(const float4*)&X[xrow * D + g * 8 + 4];
            }
            bf16x8 a;
            a[0] = (short)f2bf(xa.x); a[1] = (short)f2bf(xa.y);
            a[2] = (short)f2bf(xa.z); a[3] = (short)f2bf(xa.w);
            a[4] = (short)f2bf(xb.x); a[5] = (short)f2bf(xb.y);
            a[6] = (short)f2bf(xb.z); a[7] = (short)f2bf(xb.w);
            #pragma unroll
            for (int nt = 0; nt < 8; ++nt) {
                int nrow = nt * 16 + (l & 15);
                bf16x8 b = *(bf16x8*)&sB[nrow * D + ((g ^ (nrow & 7)) << 3)];
                acc[nt] = __builtin_amdgcn_mfma_f32_16x16x32_bf16(a, b, acc[nt], 0, 0, 0);
            }
        }

        float rmax[4];
        #pragma unroll
        for (int r = 0; r < 4; ++r) {
            float m = 0.f;
            #pragma unroll
            for (int nt = 0; nt < 8; ++nt) m = fmaxf(m, fabsf(acc[nt][r]));
            #pragma unroll
            for (int d = 1; d < 16; d <<= 1) m = fmaxf(m, __shfl_xor(m, d, 64));
            rmax[r] = fmaxf(m, 1e-20f);
        }

        #pragma unroll
        for (int r = 0; r < 4; ++r) {
            float qs = 127.0f / rmax[r];
            int row = w * 16 + (l >> 4) * 4 + r;
            int m = r0 + row;
            if (m < N_NODES) {
                char q8[8];
                #pragma unroll
                for (int nt = 0; nt < 8; ++nt) {
                    float f = acc[nt][r] * qs;
                    f = fminf(fmaxf(f, -127.0f), 127.0f);
                    q8[nt] = (char)__float2int_rn(f);
                }
                #pragma unroll
                for (int nt = 0; nt < 8; ++nt)
                    XWq[(size_t)m * D + nt * 16 + (l & 15)] = q8[nt];
                if ((l & 15) == 0) ivs[m * 2 + 1] = rmax[r] * (1.0f / 127.0f);
            }
        }
        return;
    }

    // ---------------- pass D: bucket sort, segments padded to 4 ----------------
    unsigned int* lcnt = (unsigned int*)sB;       // [256]
    int* off_l = ((int*)sB) + 256;                // [256]
    int k = bid;
    int base = k * CAP;
    int tot = TOT[k];

    lcnt[t] = 0;
    __syncthreads();
    for (int i = t; i < tot; i += 256)
        atomicAdd(&lcnt[rec[base + i] >> 16], 1u);
    __syncthreads();

    int v = (int)lcnt[t];
    int vr = (v + 3) & ~3;                        // 4-padded segment
    int s = vr;
    #pragma unroll
    for (int d = 1; d < 64; d <<= 1) {
        int u = __shfl_up(s, d, 64);
        if (l >= d) s += u;
    }
    if (l == 63) wtot[w] = s;
    __syncthreads();
    if (t == 0) {
        woff[0] = 0; woff[1] = wtot[0];
        woff[2] = wtot[0] + wtot[1]; woff[3] = wtot[0] + wtot[1] + wtot[2];
    }
    __syncthreads();
    int excl = s - vr + woff[w];
    off_l[t] = excl;
    int node = k * 256 + t;
    if (node < N_NODES) {
        deg[node] = v;
        ivs[node * 2] = rsqrtf((float)v + 1.0f);
        offs[node] = base + excl;
    }
    for (int j = v; j < vr; ++j) csr[base + excl + j] = 0;
    __syncthreads();
    lcnt[t] = 0;
    __syncthreads();
    for (int i = t; i < tot; i += 256) {
        unsigned int rc = rec[base + i];
        int dl = rc >> 16;
        unsigned int r = atomicAdd(&lcnt[dl], 1u);
        csr[base + off_l[dl] + (int)r] = (unsigned short)(rc & 0xFFFFu);
    }
}

// ---- launch 5: aggregate — ONE WAVE PER NODE (divergence-free), 16 edges/iter ----
__global__ __launch_bounds__(256) void k_agg(const char* __restrict__ XWq,
                                             const float2* __restrict__ ivs,
                                             const unsigned short* __restrict__ csr,
                                             const int* __restrict__ offs,
                                             const int* __restrict__ deg,
                                             float* __restrict__ out) {
    int node = (blockIdx.x * 256 + threadIdx.x) >> 6;   // one wave per node
    if (node >= N_NODES) return;
    int l = threadIdx.x & 63;
    int eg = l >> 4;        // edge slot 0..3
    int cl = l & 15;        // 8-byte feature chunk

    int start = offs[node];
    int cnt = deg[node];
    float2 vs = ivs[node];
    float invd = vs.x;

    float acc[8];
    #pragma unroll
    for (int j = 0; j < 8; ++j) acc[j] = 0.f;
    if (eg == 0) {   // self term
        float sc = invd * invd * vs.y;
        uint2 v = *(const uint2*)&XWq[(size_t)node * D + cl * 8];
        acc[0] = sc * sb(v.x, 0); acc[1] = sc * sb(v.x, 1);
        acc[2] = sc * sb(v.x, 2); acc[3] = sc * sb(v.x, 3);
        acc[4] = sc * sb(v.y, 0); acc[5] = sc * sb(v.y, 1);
        acc[6] = sc * sb(v.y, 2); acc[7] = sc * sb(v.y, 3);
    }

    for (int e = 0; e < cnt; e += 16) {
        // 16 edges: 4 broadcast quads; slot eg takes edge e + 4*q + eg
        uint2 q0 = *(const uint2*)&csr[start + e];
        uint2 q1 = *(const uint2*)&csr[start + e + 4];
        uint2 q2 = *(const uint2*)&csr[start + e + 8];
        uint2 q3 = *(const uint2*)&csr[start + e + 12];
        int si[4];
        {
            unsigned int h0 = (eg & 2) ? q0.y : q0.x;
            unsigned int h1 = (eg & 2) ? q1.y : q1.x;
            unsigned int h2 = (eg & 2) ? q2.y : q2.x;
            unsigned int h3 = (eg & 2) ? q3.y : q3.x;
            si[0] = (eg & 1) ? (h0 >> 16) : (h0 & 0xffff);
            si[1] = (eg & 1) ? (h1 >> 16) : (h1 & 0xffff);
            si[2] = (eg & 1) ? (h2 >> 16) : (h2 & 0xffff);
            si[3] = (eg & 1) ? (h3 >> 16) : (h3 & 0xffff);
        }
        uint2 v[4];
        float nn[4];
        #pragma unroll
        for (int u = 0; u < 4; ++u) {
            v[u] = *(const uint2*)&XWq[(size_t)si[u] * D + cl * 8];
            float2 iv = ivs[si[u]];
            nn[u] = (e + u * 4 + eg < cnt) ? invd * iv.x * iv.y : 0.f;
        }
        #pragma unroll
        for (int u = 0; u < 4; ++u) {
            float n = nn[u];
            acc[0] += n * sb(v[u].x, 0); acc[1] += n * sb(v[u].x, 1);
            acc[2] += n * sb(v[u].x, 2); acc[3] += n * sb(v[u].x, 3);
            acc[4] += n * sb(v[u].y, 0); acc[5] += n * sb(v[u].y, 1);
            acc[6] += n * sb(v[u].y, 2); acc[7] += n * sb(v[u].y, 3);
        }
    }

    // reduce across the 4 edge slots
    #pragma unroll
    for (int j = 0; j < 8; ++j) {
        acc[j] += __shfl_xor(acc[j], 16, 64);
        acc[j] += __shfl_xor(acc[j], 32, 64);
    }

    if (l < 16) {
        f32x4 o0 = (f32x4){acc[0], acc[1], acc[2], acc[3]};
        f32x4 o1 = (f32x4){acc[4], acc[5], acc[6], acc[7]};
        __builtin_nontemporal_store(o0, (f32x4*)&out[node * D + cl * 8]);
        __builtin_nontemporal_store(o1, (f32x4*)&out[node * D + cl * 8 + 4]);
    }
}

extern "C" void kernel_launch(void* const* d_in, const int* in_sizes, int n_in,
                              void* d_out, int out_size, void* d_ws, size_t ws_size,
                              hipStream_t stream) {
    const float* X = (const float*)d_in[0];
    const float* W = (const float*)d_in[1];
    const int* esrc = (const int*)d_in[2];
    const int* edst = (const int*)d_in[3];
    float* out = (float*)d_out;

    char* ws = (char*)d_ws;
    int* TOT = (int*)(ws + OFF_TOT);
    unsigned short* Wt = (unsigned short*)(ws + OFF_WT);
    int* H = (int*)(ws + OFF_H);
    int* BB = (int*)(ws + OFF_BB);
    int* deg = (int*)(ws + OFF_DEG);
    int* offs = (int*)(ws + OFF_OFFS);
    float* ivs = (float*)(ws + OFF_IVS);
    unsigned int* rec = (unsigned int*)(ws + OFF_REC);
    unsigned short* csr = (unsigned short*)(ws + OFF_CSR);
    char* XWq = (char*)(ws + OFF_XWQ);

    k_pre<<<NBLK + 64, 256, 0, stream>>>(edst, H, W, Wt);
    k_pB<<<NBKT, 256, 0, stream>>>(H, BB, TOT);
    k_pC<<<NBLK, 512, 0, stream>>>(esrc, edst, BB, rec);
    k_mid<<<NBKT + NB_GEMM, 256, 0, stream>>>(rec, TOT, deg, offs, ivs, csr,
                                              X, Wt, XWq);
    k_agg<<<(N_NODES * 64 + 255) / 256, 256, 0, stream>>>(XWq, (const float2*)ivs,
                                                          csr, offs, deg, out);
}

// Round 21
// 61.580 us; speedup vs baseline: 1.0556x; 1.0556x over previous
//
#include <hip/hip_runtime.h>

#define N_NODES 50000
#define N_EDGES 800000
#define D 128

#define NBLK 250                  // partition blocks (edge base 16B-aligned)
#define EPB (N_EDGES / NBLK)      // 3200 edges per block
#define NQ (EPB / 4)              // 800 int4 quads per block
#define NBKT 196                  // coarse buckets of 256 nodes
#define CAP 6144                  // fixed slots per bucket

typedef __attribute__((ext_vector_type(8))) short bf16x8;
typedef __attribute__((ext_vector_type(4))) float f32x4;

// ---------------- workspace layout (bytes) ----------------
static const size_t OFF_TOT  = 0;          // int[196] bucket edge count
static const size_t OFF_WT   = 1024;       // ushort[128*128] bf16 W^T [n][k]
static const size_t OFF_H    = 33792;      // int[196*256] per-(bucket,block) counts (stride 256)
static const size_t OFF_BB   = 234496;     // int[196*256] rel scatter bases (stride 256)
static const size_t OFF_DEG  = 435200;     // int[50000]
static const size_t OFF_OFFS = 635200;     // int[50000]
static const size_t OFF_IVS  = 835200;     // float2[50000] {inv, scale}
static const size_t OFF_REC  = 1235200;    // uint[196*6144] (src | dstLocal<<16)
static const size_t OFF_CSR  = 6052096;    // ushort[196*6144]
static const size_t OFF_XWQ  = 8460544;    // int8[50000*128]
// total: 14,860,544 bytes

#define BM 64
#define NB_GEMM ((N_NODES + BM - 1) / BM)   // 782

__device__ __forceinline__ unsigned short f2bf(float f) {
    unsigned int u = __float_as_uint(f);
    unsigned int r = (u + 0x7fffu + ((u >> 16) & 1u)) >> 16;   // RNE
    return (unsigned short)r;
}
__device__ __forceinline__ float sb(unsigned int u, int i) {
    return (float)((int)(u << (24 - 8 * i)) >> 24);
}

// ---- launch 1: pass-A histogram (blocks 0..249, int4 edge loads) ∥ Wt conv (250..313) ----
__global__ __launch_bounds__(256) void k_pre(const int* __restrict__ dst,
                                             int* __restrict__ H,
                                             const float* __restrict__ W,
                                             unsigned short* __restrict__ Wt) {
    __shared__ unsigned int cnt[256];
    int bid = blockIdx.x, t = threadIdx.x;
    if (bid >= NBLK) {
        int idx = (bid - NBLK) * 256 + t;   // 0..16383
        int n = idx >> 7, k = idx & 127;
        Wt[n * D + k] = f2bf(W[k * D + n]);
        return;
    }
    cnt[t] = 0;
    __syncthreads();
    int e0 = bid * EPB;
    for (int q = t; q < NQ; q += 256) {
        int4 d4 = *(const int4*)&dst[e0 + q * 4];
        atomicAdd(&cnt[d4.x >> 8], 1u);
        atomicAdd(&cnt[d4.y >> 8], 1u);
        atomicAdd(&cnt[d4.z >> 8], 1u);
        atomicAdd(&cnt[d4.w >> 8], 1u);
    }
    __syncthreads();
    if (t < NBKT) H[t * 256 + bid] = (int)cnt[t];
}

// ---- launch 2: per-bucket scan over blocks (independent) ----
__global__ __launch_bounds__(256) void k_pB(const int* __restrict__ H,
                                            int* __restrict__ BB,
                                            int* __restrict__ TOT) {
    int k = blockIdx.x, t = threadIdx.x;
    int w = t >> 6, l = t & 63;
    int v = (t < NBLK) ? H[k * 256 + t] : 0;
    int s = v;
    #pragma unroll
    for (int d = 1; d < 64; d <<= 1) {
        int u = __shfl_up(s, d, 64);
        if (l >= d) s += u;
    }
    __shared__ int wtot[4], woff[4];
    if (l == 63) wtot[w] = s;
    __syncthreads();
    if (t == 0) {
        woff[0] = 0; woff[1] = wtot[0];
        woff[2] = wtot[0] + wtot[1]; woff[3] = wtot[0] + wtot[1] + wtot[2];
    }
    __syncthreads();
    int excl = s - v + woff[w];
    BB[k * 256 + t] = excl;
    if (t == 255) TOT[k] = excl + v;
}

// ---- launch 3: rank-capturing re-histogram + record scatter (int4 edge loads) ----
__global__ __launch_bounds__(512) void k_pC(const int* __restrict__ src,
                                            const int* __restrict__ dst,
                                            const int* __restrict__ BB,
                                            unsigned int* __restrict__ rec) {
    __shared__ unsigned int cnt[200];
    __shared__ int myBB[NBKT];
    int b = blockIdx.x, t = threadIdx.x;
    if (t < 200) cnt[t] = 0;
    if (t < NBKT) myBB[t] = t * CAP + BB[t * 256 + b];
    __syncthreads();
    int e0 = b * EPB;
    for (int q = t; q < NQ; q += 512) {
        int4 d4 = *(const int4*)&dst[e0 + q * 4];
        int4 s4 = *(const int4*)&src[e0 + q * 4];
        {
            int k = d4.x >> 8;
            unsigned int r = atomicAdd(&cnt[k], 1u);
            rec[myBB[k] + (int)r] = (unsigned int)s4.x | ((unsigned int)(d4.x & 255) << 16);
        }
        {
            int k = d4.y >> 8;
            unsigned int r = atomicAdd(&cnt[k], 1u);
            rec[myBB[k] + (int)r] = (unsigned int)s4.y | ((unsigned int)(d4.y & 255) << 16);
        }
        {
            int k = d4.z >> 8;
            unsigned int r = atomicAdd(&cnt[k], 1u);
            rec[myBB[k] + (int)r] = (unsigned int)s4.z | ((unsigned int)(d4.z & 255) << 16);
        }
        {
            int k = d4.w >> 8;
            unsigned int r = atomicAdd(&cnt[k], 1u);
            rec[myBB[k] + (int)r] = (unsigned int)s4.w | ((unsigned int)(d4.w & 255) << 16);
        }
    }
}

// ---- launch 4: pass D (blocks 0..195) ∥ GEMM (A direct from global) + int8 quant ----
__global__ __launch_bounds__(256) void k_mid(const unsigned int* __restrict__ rec,
                                             const int* __restrict__ TOT,
                                             int* __restrict__ deg,
                                             int* __restrict__ offs,
                                             float* __restrict__ ivs,
                                             unsigned short* __restrict__ csr,
                                             const float* __restrict__ X,
                                             const unsigned short* __restrict__ Wt,
                                             char* __restrict__ XWq) {
    __shared__ unsigned short sB[D * D];     // 32KB (gemm B) / pD scratch
    __shared__ int wtot[4], woff[4];
    int bid = blockIdx.x;
    int t = threadIdx.x;
    int w = t >> 6, l = t & 63;

    if (bid >= NBKT) {
        // ---------------- GEMM + per-row int8 quantization ----------------
        int r0 = (bid - NBKT) * BM;

        #pragma unroll
        for (int p = 0; p < 8; ++p) {
            int e = p * 2048 + t * 8;
            int n = e >> 7, k = e & 127;
            uint4 v = *(const uint4*)&Wt[e];
            int idx = n * D + (((k >> 3) ^ (n & 7)) << 3);
            *(uint4*)&sB[idx] = v;
        }
        __syncthreads();

        int arow = w * 16 + (l & 15);
        int xrow = r0 + arow;
        bool okr = (xrow < N_NODES);
        f32x4 acc[8];
        #pragma unroll
        for (int i = 0; i < 8; ++i) acc[i] = (f32x4){0.f, 0.f, 0.f, 0.f};

        #pragma unroll
        for (int kk = 0; kk < 4; ++kk) {
            int g = kk * 4 + (l >> 4);
            float4 xa = make_float4(0.f, 0.f, 0.f, 0.f);
            float4 xb = make_float4(0.f, 0.f, 0.f, 0.f);
            if (okr) {
                xa = *(const float4*)&X[xrow * D + g * 8];
                xb = *(const float4*)&X[xrow * D + g * 8 + 4];
            }
            bf16x8 a;
            a[0] = (short)f2bf(xa.x); a[1] = (short)f2bf(xa.y);
            a[2] = (short)f2bf(xa.z); a[3] = (short)f2bf(xa.w);
            a[4] = (short)f2bf(xb.x); a[5] = (short)f2bf(xb.y);
            a[6] = (short)f2bf(xb.z); a[7] = (short)f2bf(xb.w);
            #pragma unroll
            for (int nt = 0; nt < 8; ++nt) {
                int nrow = nt * 16 + (l & 15);
                bf16x8 b = *(bf16x8*)&sB[nrow * D + ((g ^ (nrow & 7)) << 3)];
                acc[nt] = __builtin_amdgcn_mfma_f32_16x16x32_bf16(a, b, acc[nt], 0, 0, 0);
            }
        }

        float rmax[4];
        #pragma unroll
        for (int r = 0; r < 4; ++r) {
            float m = 0.f;
            #pragma unroll
            for (int nt = 0; nt < 8; ++nt) m = fmaxf(m, fabsf(acc[nt][r]));
            #pragma unroll
            for (int d = 1; d < 16; d <<= 1) m = fmaxf(m, __shfl_xor(m, d, 64));
            rmax[r] = fmaxf(m, 1e-20f);
        }

        // quantize and store directly (each lane owns cols (l&15) of its rows)
        #pragma unroll
        for (int r = 0; r < 4; ++r) {
            float qs = 127.0f / rmax[r];
            int row = w * 16 + (l >> 4) * 4 + r;
            int m = r0 + row;
            if (m < N_NODES) {
                char q8[8];
                #pragma unroll
                for (int nt = 0; nt < 8; ++nt) {
                    float f = acc[nt][r] * qs;
                    f = fminf(fmaxf(f, -127.0f), 127.0f);
                    q8[nt] = (char)__float2int_rn(f);
                }
                #pragma unroll
                for (int nt = 0; nt < 8; ++nt)
                    XWq[(size_t)m * D + nt * 16 + (l & 15)] = q8[nt];
                if ((l & 15) == 0) ivs[m * 2 + 1] = rmax[r] * (1.0f / 127.0f);
            }
        }
        return;
    }

    // ---------------- pass D: bucket sort, segments padded to 4 ----------------
    unsigned int* lcnt = (unsigned int*)sB;       // [256]
    int* off_l = ((int*)sB) + 256;                // [256]
    int k = bid;
    int base = k * CAP;
    int tot = TOT[k];

    lcnt[t] = 0;
    __syncthreads();
    for (int i = t; i < tot; i += 256)
        atomicAdd(&lcnt[rec[base + i] >> 16], 1u);
    __syncthreads();

    int v = (int)lcnt[t];
    int vr = (v + 3) & ~3;                        // 4-padded segment
    int s = vr;
    #pragma unroll
    for (int d = 1; d < 64; d <<= 1) {
        int u = __shfl_up(s, d, 64);
        if (l >= d) s += u;
    }
    if (l == 63) wtot[w] = s;
    __syncthreads();
    if (t == 0) {
        woff[0] = 0; woff[1] = wtot[0];
        woff[2] = wtot[0] + wtot[1]; woff[3] = wtot[0] + wtot[1] + wtot[2];
    }
    __syncthreads();
    int excl = s - vr + woff[w];
    off_l[t] = excl;
    int node = k * 256 + t;
    if (node < N_NODES) {
        deg[node] = v;
        ivs[node * 2] = rsqrtf((float)v + 1.0f);
        offs[node] = base + excl;
    }
    for (int j = v; j < vr; ++j) csr[base + excl + j] = 0;
    __syncthreads();
    lcnt[t] = 0;
    __syncthreads();
    for (int i = t; i < tot; i += 256) {
        unsigned int rc = rec[base + i];
        int dl = rc >> 16;
        unsigned int r = atomicAdd(&lcnt[dl], 1u);
        csr[base + off_l[dl] + (int)r] = (unsigned short)(rc & 0xFFFFu);
    }
}

// ---- launch 5: aggregate — 16-lane group per node, uint2 csr quads, 8-deep ----
__global__ __launch_bounds__(256) void k_agg(const char* __restrict__ XWq,
                                             const float2* __restrict__ ivs,
                                             const unsigned short* __restrict__ csr,
                                             const int* __restrict__ offs,
                                             const int* __restrict__ deg,
                                             float* __restrict__ out) {
    __shared__ int s_off[16];
    __shared__ int s_cnt[16];
    __shared__ float2 s_iv[16];
    int n0 = blockIdx.x * 16;
    int t = threadIdx.x;
    if (t < 16) {
        int n = n0 + t;
        int ok = (n < N_NODES);
        s_off[t] = ok ? offs[n] : 0;
        s_cnt[t] = ok ? deg[n] : -1;
        s_iv[t] = ok ? ivs[n] : make_float2(0.f, 0.f);
    }
    __syncthreads();
    int li = t >> 4;
    int cl = t & 15;
    int node = n0 + li;
    int cnt = s_cnt[li];
    if (cnt < 0) return;
    int start = s_off[li];
    float2 vs = s_iv[li];
    float invd = vs.x;

    float acc[8];
    {   // self term
        float sc = invd * invd * vs.y;
        uint2 v = *(const uint2*)&XWq[(size_t)node * D + cl * 8];
        acc[0] = sc * sb(v.x, 0); acc[1] = sc * sb(v.x, 1);
        acc[2] = sc * sb(v.x, 2); acc[3] = sc * sb(v.x, 3);
        acc[4] = sc * sb(v.y, 0); acc[5] = sc * sb(v.y, 1);
        acc[6] = sc * sb(v.y, 2); acc[7] = sc * sb(v.y, 3);
    }

    for (int e = 0; e < cnt; e += 8) {
        uint2 ca = *(const uint2*)&csr[start + e];
        uint2 cb = *(const uint2*)&csr[start + e + 4];
        int si[8];
        si[0] = ca.x & 0xffff; si[1] = ca.x >> 16;
        si[2] = ca.y & 0xffff; si[3] = ca.y >> 16;
        si[4] = cb.x & 0xffff; si[5] = cb.x >> 16;
        si[6] = cb.y & 0xffff; si[7] = cb.y >> 16;
        uint2 v[8];
        float nn[8];
        #pragma unroll
        for (int u = 0; u < 8; ++u) {
            v[u] = *(const uint2*)&XWq[(size_t)si[u] * D + cl * 8];
            float2 iv = ivs[si[u]];
            nn[u] = (e + u < cnt) ? invd * iv.x * iv.y : 0.f;
        }
        #pragma unroll
        for (int u = 0; u < 8; ++u) {
            float n = nn[u];
            acc[0] += n * sb(v[u].x, 0); acc[1] += n * sb(v[u].x, 1);
            acc[2] += n * sb(v[u].x, 2); acc[3] += n * sb(v[u].x, 3);
            acc[4] += n * sb(v[u].y, 0); acc[5] += n * sb(v[u].y, 1);
            acc[6] += n * sb(v[u].y, 2); acc[7] += n * sb(v[u].y, 3);
        }
    }

    f32x4 o0 = (f32x4){acc[0], acc[1], acc[2], acc[3]};
    f32x4 o1 = (f32x4){acc[4], acc[5], acc[6], acc[7]};
    __builtin_nontemporal_store(o0, (f32x4*)&out[node * D + cl * 8]);
    __builtin_nontemporal_store(o1, (f32x4*)&out[node * D + cl * 8 + 4]);
}

extern "C" void kernel_launch(void* const* d_in, const int* in_sizes, int n_in,
                              void* d_out, int out_size, void* d_ws, size_t ws_size,
                              hipStream_t stream) {
    const float* X = (const float*)d_in[0];
    const float* W = (const float*)d_in[1];
    const int* esrc = (const int*)d_in[2];
    const int* edst = (const int*)d_in[3];
    float* out = (float*)d_out;

    char* ws = (char*)d_ws;
    int* TOT = (int*)(ws + OFF_TOT);
    unsigned short* Wt = (unsigned short*)(ws + OFF_WT);
    int* H = (int*)(ws + OFF_H);
    int* BB = (int*)(ws + OFF_BB);
    int* deg = (int*)(ws + OFF_DEG);
    int* offs = (int*)(ws + OFF_OFFS);
    float* ivs = (float*)(ws + OFF_IVS);
    unsigned int* rec = (unsigned int*)(ws + OFF_REC);
    unsigned short* csr = (unsigned short*)(ws + OFF_CSR);
    char* XWq = (char*)(ws + OFF_XWQ);

    k_pre<<<NBLK + 64, 256, 0, stream>>>(edst, H, W, Wt);
    k_pB<<<NBKT, 256, 0, stream>>>(H, BB, TOT);
    k_pC<<<NBLK, 512, 0, stream>>>(esrc, edst, BB, rec);
    k_mid<<<NBKT + NB_GEMM, 256, 0, stream>>>(rec, TOT, deg, offs, ivs, csr,
                                              X, Wt, XWq);
    k_agg<<<(N_NODES + 15) / 16, 256, 0, stream>>>(XWq, (const float2*)ivs, csr,
                                                   offs, deg, out);
}